// Round 2
// baseline (258.592 us; speedup 1.0000x reference)
//
#include <hip/hip_runtime.h>

// PhaseMultiHeadAttention: B=8, N=1024, D=512, H=8, dh=64
// Pipeline: fused cvt->bf16 | QKV GEMM (MFMA, V stored transposed) |
//           flash attn w/ relative skew (shfl-skew, 2 barriers/iter) | out GEMM
// rel[n,m] = Q[n] . E_rel[m-n+N-1]

typedef __bf16 bf16x8 __attribute__((ext_vector_type(8)));
typedef __bf16 bf16x4 __attribute__((ext_vector_type(4)));
typedef float  f32x4  __attribute__((ext_vector_type(4)));

#if __has_builtin(__builtin_amdgcn_exp2f)
#define EXP2(x) __builtin_amdgcn_exp2f(x)
#else
#define EXP2(x) exp2f(x)
#endif

// ---------------- fused fp32 -> bf16 conversion (all 6 tensors) ----------------
// v4 ranges: x[0,1048576) E[..1081328) Wq[..1146864) Wk[..1212400) Wv[..1277936) Wo[..1343472)
__global__ __launch_bounds__(256) void cvt_all(const float* __restrict__ x,
                                               const float* __restrict__ E,
                                               const float* __restrict__ wq,
                                               const float* __restrict__ wk,
                                               const float* __restrict__ wv,
                                               const float* __restrict__ wo,
                                               __bf16* __restrict__ xb,
                                               __bf16* __restrict__ Eb,
                                               __bf16* __restrict__ wqkv,
                                               __bf16* __restrict__ wob) {
    int i = blockIdx.x * 256 + threadIdx.x;
    const float* s; __bf16* d; int off;
    if      (i < 1048576) { s = x;  d = xb;            off = i; }
    else if (i < 1081328) { s = E;  d = Eb;            off = i - 1048576; }
    else if (i < 1146864) { s = wq; d = wqkv;          off = i - 1081328; }
    else if (i < 1212400) { s = wk; d = wqkv + 262144; off = i - 1146864; }
    else if (i < 1277936) { s = wv; d = wqkv + 524288; off = i - 1212400; }
    else if (i < 1343472) { s = wo; d = wob;           off = i - 1277936; }
    else return;
    float4 v = *(const float4*)(s + (size_t)off * 4);
    bf16x4 o;
    o[0] = (__bf16)v.x; o[1] = (__bf16)v.y; o[2] = (__bf16)v.z; o[3] = (__bf16)v.w;
    *(bf16x4*)(d + (size_t)off * 4) = o;
}

// ---------------- QKV projection GEMM ----------------
// C[m][j] = sum_k X[m][k] * W[j][k];  M=8192, N=1536 (q|k|v), K=512
// Q,K scattered as [B,H,N,dh]; V scattered TRANSPOSED as [B,H,dh,N].
__global__ __launch_bounds__(256) void gemm_qkv(const __bf16* __restrict__ X,
                                                const __bf16* __restrict__ W,
                                                __bf16* __restrict__ Qb,
                                                __bf16* __restrict__ Kb,
                                                __bf16* __restrict__ VbT) {
    __shared__ __bf16 Xs[128][72];
    __shared__ __bf16 Ws[128][72];
    const int tid = threadIdx.x;
    const int wave = tid >> 6, lane = tid & 63;
    const int col = lane & 15, quad = lane >> 4;
    const int m_base = blockIdx.x * 128;
    const int j_base = blockIdx.y * 128;
    const int wm = (wave & 1) * 64;
    const int wn = (wave >> 1) * 64;
    const f32x4 fz = {0.f, 0.f, 0.f, 0.f};
    f32x4 acc[4][4];
#pragma unroll
    for (int i = 0; i < 4; ++i)
#pragma unroll
        for (int j = 0; j < 4; ++j) acc[i][j] = fz;

    const int r = tid >> 3, c8 = (tid & 7) * 8;
    for (int k0 = 0; k0 < 512; k0 += 64) {
#pragma unroll
        for (int p = 0; p < 4; ++p) {
            *(bf16x8*)(&Xs[r + p * 32][c8]) =
                *(const bf16x8*)(X + (size_t)(m_base + r + p * 32) * 512 + k0 + c8);
            *(bf16x8*)(&Ws[r + p * 32][c8]) =
                *(const bf16x8*)(W + (size_t)(j_base + r + p * 32) * 512 + k0 + c8);
        }
        __syncthreads();
#pragma unroll
        for (int kk = 0; kk < 64; kk += 32) {
            bf16x8 a[4], b[4];
#pragma unroll
            for (int i = 0; i < 4; ++i) a[i] = *(const bf16x8*)(&Xs[wm + i * 16 + col][kk + quad * 8]);
#pragma unroll
            for (int j = 0; j < 4; ++j) b[j] = *(const bf16x8*)(&Ws[wn + j * 16 + col][kk + quad * 8]);
#pragma unroll
            for (int i = 0; i < 4; ++i)
#pragma unroll
                for (int j = 0; j < 4; ++j)
                    acc[i][j] = __builtin_amdgcn_mfma_f32_16x16x32_bf16(a[i], b[j], acc[i][j], 0, 0, 0);
        }
        __syncthreads();
    }
#pragma unroll
    for (int i = 0; i < 4; ++i) {
#pragma unroll
        for (int rr = 0; rr < 4; ++rr) {
            int m = m_base + wm + i * 16 + quad * 4 + rr;
            int b_ = m >> 10, n = m & 1023;
#pragma unroll
            for (int j = 0; j < 4; ++j) {
                int jabs = j_base + wn + j * 16 + col;
                int which = jabs >> 9, rem = jabs & 511;
                int h = rem >> 6, d = rem & 63;
                __bf16 val = (__bf16)acc[i][j][rr];
                if (which == 0)
                    Qb[(((size_t)b_ * 8 + h) * 1024 + n) * 64 + d] = val;
                else if (which == 1)
                    Kb[(((size_t)b_ * 8 + h) * 1024 + n) * 64 + d] = val;
                else
                    VbT[(((size_t)b_ * 8 + h) * 64 + d) * 1024 + n] = val;  // transposed
            }
        }
    }
}

// ---------------- flash attention with relative skew ----------------
// grid: x = 16 (n-tiles of 64), y = 64 (b*h). 256 threads = 4 waves, 16 rows each.
__global__ __launch_bounds__(256, 4) void flash_kernel(const __bf16* __restrict__ Qb,
                                                       const __bf16* __restrict__ Kb,
                                                       const __bf16* __restrict__ VbT,
                                                       const __bf16* __restrict__ Eb,
                                                       const float* __restrict__ phase,
                                                       __bf16* __restrict__ Ob) {
    const int bh = blockIdx.y;
    const int n0 = blockIdx.x * 64;
    const int tid = threadIdx.x;
    const int wave = tid >> 6, lane = tid & 63;
    const int col = lane & 15, quad = lane >> 4;

    __shared__ __bf16 Ks[64][72];        // K tile [m][k]   (row pitch 144B: 16B-aligned, 2-way banks)
    __shared__ __bf16 Vt[64][72];        // V^T tile [d][m]
    __shared__ __bf16 Pw[4][16][72];     // per-wave P [row][m-local] (wave-private: no barrier)

    const f32x4 fz = {0.f, 0.f, 0.f, 0.f};
    const __bf16* Qrow = Qb + ((size_t)bh * 1024 + n0 + wave * 16 + col) * 64;
    const bf16x8 a_q0 = *(const bf16x8*)(Qrow + quad * 8);
    const bf16x8 a_q1 = *(const bf16x8*)(Qrow + 32 + quad * 8);

    f32x4 o_acc[4];
#pragma unroll
    for (int j = 0; j < 4; ++j) o_acc[j] = fz;
    float l_part[4] = {0.f, 0.f, 0.f, 0.f};

    // staging indices: each thread 2x b128 per tensor
    const int sr = tid >> 2, sc = (tid & 3) * 16;
    const __bf16* Kbase = Kb + (size_t)bh * 1024 * 64;
    const __bf16* VTbase = VbT + (size_t)bh * 64 * 1024;
    // E fragment base (direct from global; window coord gE = m0-n0+1008-16w + c*16+col)
    const __bf16* eb0 = Eb + (size_t)(1008 - n0 - 16 * wave + col) * 64 + quad * 8;

#pragma unroll 1
    for (int m0 = 0; m0 < 1024; m0 += 64) {
        // ---- stage K and V^T (vector b128, no transpose in-kernel) ----
        *(bf16x8*)(&Ks[sr][sc])     = *(const bf16x8*)(Kbase + (size_t)(m0 + sr) * 64 + sc);
        *(bf16x8*)(&Ks[sr][sc + 8]) = *(const bf16x8*)(Kbase + (size_t)(m0 + sr) * 64 + sc + 8);
        *(bf16x8*)(&Vt[sr][sc])     = *(const bf16x8*)(VTbase + (size_t)sr * 1024 + m0 + sc);
        *(bf16x8*)(&Vt[sr][sc + 8]) = *(const bf16x8*)(VTbase + (size_t)sr * 1024 + m0 + sc + 8);
        __syncthreads();

        // ---- QE strip: 5 col-blocks of Q_w(16x64) @ E_win^T, E frags from global (L2-hot) ----
        f32x4 qe[5];
        const __bf16* eE = eb0 + (size_t)m0 * 64;
#pragma unroll
        for (int c = 0; c < 5; ++c) {
            bf16x8 be0 = *(const bf16x8*)(eE + c * 1024);
            bf16x8 be1 = *(const bf16x8*)(eE + c * 1024 + 32);
            qe[c] = __builtin_amdgcn_mfma_f32_16x16x32_bf16(a_q0, be0, fz, 0, 0, 0);
            qe[c] = __builtin_amdgcn_mfma_f32_16x16x32_bf16(a_q1, be1, qe[c], 0, 0, 0);
        }

        // ---- skew via shfl: rel[jb][rr] = QE[row][jb*16+col + 15-row], row=quad*4+rr ----
        float rel[4][4];
#pragma unroll
        for (int rr = 0; rr < 4; ++rr) {
            int t = col + 15 - (quad * 4 + rr);      // col + shift, in [0,30]
            int src = (t & 15) | (lane & 48);        // same quad, rotated col
            int sel = t >> 4;                        // 0 -> block jb, 1 -> block jb+1
            float va[5];
#pragma unroll
            for (int c = 0; c < 5; ++c) va[c] = __shfl(qe[c][rr], src, 64);
#pragma unroll
            for (int jb = 0; jb < 4; ++jb) rel[jb][rr] = sel ? va[jb + 1] : va[jb];
        }

        // ---- S = QK^T + rel, exp2, write P (wave-private Pw) ----
#pragma unroll
        for (int jb = 0; jb < 4; ++jb) {
            bf16x8 bk0 = *(const bf16x8*)(&Ks[jb * 16 + col][quad * 8]);
            bf16x8 bk1 = *(const bf16x8*)(&Ks[jb * 16 + col][32 + quad * 8]);
            f32x4 s = __builtin_amdgcn_mfma_f32_16x16x32_bf16(a_q0, bk0, fz, 0, 0, 0);
            s = __builtin_amdgcn_mfma_f32_16x16x32_bf16(a_q1, bk1, s, 0, 0, 0);
#pragma unroll
            for (int rr = 0; rr < 4; ++rr) {
                float p = EXP2((s[rr] + rel[jb][rr]) * 0.18033688f);  // scale*log2(e), scale=1/8
                l_part[rr] += p;
                Pw[wave][quad * 4 + rr][jb * 16 + col] = (__bf16)p;
            }
        }
        // wave-private LDS RAW: drain DS queue, no block barrier needed
        asm volatile("s_waitcnt lgkmcnt(0)" ::: "memory");

        // ---- O += P @ V ----
        {
            bf16x8 ap0 = *(const bf16x8*)(&Pw[wave][col][quad * 8]);
            bf16x8 ap1 = *(const bf16x8*)(&Pw[wave][col][32 + quad * 8]);
#pragma unroll
            for (int jd = 0; jd < 4; ++jd) {
                bf16x8 bv0 = *(const bf16x8*)(&Vt[jd * 16 + col][quad * 8]);
                bf16x8 bv1 = *(const bf16x8*)(&Vt[jd * 16 + col][32 + quad * 8]);
                o_acc[jd] = __builtin_amdgcn_mfma_f32_16x16x32_bf16(ap0, bv0, o_acc[jd], 0, 0, 0);
                o_acc[jd] = __builtin_amdgcn_mfma_f32_16x16x32_bf16(ap1, bv1, o_acc[jd], 0, 0, 0);
            }
        }
        __syncthreads();
    }

    // ---- epilogue: O * phase / l -> Ob[b][n][h*64+d] ----
    const int b_ = bh >> 3, h = bh & 7;
#pragma unroll
    for (int rr = 0; rr < 4; ++rr) {
        float l = l_part[rr];
        l += __shfl_xor(l, 1, 16);
        l += __shfl_xor(l, 2, 16);
        l += __shfl_xor(l, 4, 16);
        l += __shfl_xor(l, 8, 16);
        int n_row = n0 + wave * 16 + quad * 4 + rr;
        float ph = phase[(size_t)bh * 1024 + n_row];
        float f = ph / l;
#pragma unroll
        for (int jd = 0; jd < 4; ++jd) {
            Ob[((size_t)b_ * 1024 + n_row) * 512 + h * 64 + jd * 16 + col] =
                (__bf16)(o_acc[jd][rr] * f);
        }
    }
}

// ---------------- output projection GEMM ----------------
// out[m][j] = sum_k Ob[m][k] * Wo[j][k] + b_o[j];  M=8192, N=512, K=512, fp32 out
__global__ __launch_bounds__(256) void gemm_out(const __bf16* __restrict__ X,
                                                const __bf16* __restrict__ W,
                                                const float* __restrict__ bo,
                                                float* __restrict__ out) {
    __shared__ __bf16 Xs[128][72];
    __shared__ __bf16 Ws[128][72];
    const int tid = threadIdx.x;
    const int wave = tid >> 6, lane = tid & 63;
    const int col = lane & 15, quad = lane >> 4;
    const int m_base = blockIdx.x * 128;
    const int j_base = blockIdx.y * 128;
    const int wm = (wave & 1) * 64;
    const int wn = (wave >> 1) * 64;
    const f32x4 fz = {0.f, 0.f, 0.f, 0.f};
    f32x4 acc[4][4];
#pragma unroll
    for (int i = 0; i < 4; ++i)
#pragma unroll
        for (int j = 0; j < 4; ++j) acc[i][j] = fz;

    const int r = tid >> 3, c8 = (tid & 7) * 8;
    for (int k0 = 0; k0 < 512; k0 += 64) {
#pragma unroll
        for (int p = 0; p < 4; ++p) {
            *(bf16x8*)(&Xs[r + p * 32][c8]) =
                *(const bf16x8*)(X + (size_t)(m_base + r + p * 32) * 512 + k0 + c8);
            *(bf16x8*)(&Ws[r + p * 32][c8]) =
                *(const bf16x8*)(W + (size_t)(j_base + r + p * 32) * 512 + k0 + c8);
        }
        __syncthreads();
#pragma unroll
        for (int kk = 0; kk < 64; kk += 32) {
            bf16x8 a[4], b[4];
#pragma unroll
            for (int i = 0; i < 4; ++i) a[i] = *(const bf16x8*)(&Xs[wm + i * 16 + col][kk + quad * 8]);
#pragma unroll
            for (int j = 0; j < 4; ++j) b[j] = *(const bf16x8*)(&Ws[wn + j * 16 + col][kk + quad * 8]);
#pragma unroll
            for (int i = 0; i < 4; ++i)
#pragma unroll
                for (int j = 0; j < 4; ++j)
                    acc[i][j] = __builtin_amdgcn_mfma_f32_16x16x32_bf16(a[i], b[j], acc[i][j], 0, 0, 0);
        }
        __syncthreads();
    }
#pragma unroll
    for (int i = 0; i < 4; ++i) {
#pragma unroll
        for (int j = 0; j < 4; ++j) {
            int jabs = j_base + wn + j * 16 + col;
            float bv = bo[jabs];
#pragma unroll
            for (int rr = 0; rr < 4; ++rr) {
                int m = m_base + wm + i * 16 + quad * 4 + rr;
                out[(size_t)m * 512 + jabs] = acc[i][j][rr] + bv;
            }
        }
    }
}

extern "C" void kernel_launch(void* const* d_in, const int* in_sizes, int n_in,
                              void* d_out, int out_size, void* d_ws, size_t ws_size,
                              hipStream_t stream) {
    (void)in_sizes; (void)n_in; (void)out_size; (void)ws_size;
    const float* x     = (const float*)d_in[0];
    const float* phase = (const float*)d_in[1];
    const float* E_rel = (const float*)d_in[2];
    const float* W_q   = (const float*)d_in[3];
    const float* W_k   = (const float*)d_in[4];
    const float* W_v   = (const float*)d_in[5];
    const float* W_o   = (const float*)d_in[6];
    const float* b_o   = (const float*)d_in[7];
    float* out = (float*)d_out;

    char* ws = (char*)d_ws;
    __bf16* xb   = (__bf16*)(ws);                 //  8,388,608 B
    __bf16* wqkv = (__bf16*)(ws + 8388608);       //  1,572,864 B (q|k|v rows stacked)
    __bf16* wob  = (__bf16*)(ws + 9961472);       //    524,288 B
    __bf16* Eb   = (__bf16*)(ws + 10485760);      //    262,144 B (2048 rows; row 2047 poison, unused in math)
    __bf16* Qb   = (__bf16*)(ws + 10747904);      //  8,388,608 B
    __bf16* Kb   = (__bf16*)(ws + 19136512);      //  8,388,608 B
    __bf16* VbT  = (__bf16*)(ws + 27525120);      //  8,388,608 B  [B,H,dh,N] transposed
    __bf16* Ob   = (__bf16*)(ws + 35913728);      //  8,388,608 B  -> total ~44.3 MB

    cvt_all<<<dim3(5249), dim3(256), 0, stream>>>(x, E_rel, W_q, W_k, W_v, W_o,
                                                  xb, Eb, wqkv, wob);
    gemm_qkv<<<dim3(64, 12), dim3(256), 0, stream>>>(xb, wqkv, Qb, Kb, VbT);
    flash_kernel<<<dim3(16, 64), dim3(256), 0, stream>>>(Qb, Kb, VbT, Eb, phase, Ob);
    gemm_out<<<dim3(64, 4), dim3(256), 0, stream>>>(Ob, wob, b_o, out);
}

// Round 4
// 227.830 us; speedup vs baseline: 1.1350x; 1.1350x over previous
//
#include <hip/hip_runtime.h>

// PhaseMultiHeadAttention: B=8, N=1024, D=512, H=8, dh=64
// R4 = R3 + fixed flash epilogue (store ALL 64 d-elements per row; R3 wrote half).
// Pipeline: fused cvt->bf16 | QKV GEMM (vectorized epilogues, V transposed) |
//           barrier-free flash w/ 32x32x16 MFMA + shfl skew | out GEMM.
// rel[n,m] = Q[n] . E_rel[m-n+N-1]

typedef __bf16 bf16x8 __attribute__((ext_vector_type(8)));
typedef __bf16 bf16x4 __attribute__((ext_vector_type(4)));
typedef float  f32x4  __attribute__((ext_vector_type(4)));
typedef float  f32x16 __attribute__((ext_vector_type(16)));

#if __has_builtin(__builtin_amdgcn_exp2f)
#define EXP2(x) __builtin_amdgcn_exp2f(x)
#else
#define EXP2(x) exp2f(x)
#endif

// ---------------- fused fp32 -> bf16 conversion (all 6 tensors) ----------------
__global__ __launch_bounds__(256) void cvt_all(const float* __restrict__ x,
                                               const float* __restrict__ E,
                                               const float* __restrict__ wq,
                                               const float* __restrict__ wk,
                                               const float* __restrict__ wv,
                                               const float* __restrict__ wo,
                                               __bf16* __restrict__ xb,
                                               __bf16* __restrict__ Eb,
                                               __bf16* __restrict__ wqkv,
                                               __bf16* __restrict__ wob) {
    int i = blockIdx.x * 256 + threadIdx.x;
    const float* s; __bf16* d; int off;
    if      (i < 1048576) { s = x;  d = xb;            off = i; }
    else if (i < 1081328) { s = E;  d = Eb;            off = i - 1048576; }
    else if (i < 1146864) { s = wq; d = wqkv;          off = i - 1081328; }
    else if (i < 1212400) { s = wk; d = wqkv + 262144; off = i - 1146864; }
    else if (i < 1277936) { s = wv; d = wqkv + 524288; off = i - 1212400; }
    else if (i < 1343472) { s = wo; d = wob;           off = i - 1277936; }
    else return;
    float4 v = *(const float4*)(s + (size_t)off * 4);
    bf16x4 o;
    o[0] = (__bf16)v.x; o[1] = (__bf16)v.y; o[2] = (__bf16)v.z; o[3] = (__bf16)v.w;
    *(bf16x4*)(d + (size_t)off * 4) = o;
}

// ---------------- QKV projection GEMM ----------------
// C[m][j] = sum_k X[m][k]*W[j][k]; M=8192, N=1536 (q|k|v), K=512.
// Q/K blocks: operand-swapped MFMA so acc regs run along j (=dh) -> bf16x4 stores.
// V blocks: normal order so acc regs run along m (=n) -> bf16x4 stores into VbT.
__global__ __launch_bounds__(256) void gemm_qkv(const __bf16* __restrict__ X,
                                                const __bf16* __restrict__ W,
                                                __bf16* __restrict__ Qb,
                                                __bf16* __restrict__ Kb,
                                                __bf16* __restrict__ VbT) {
    __shared__ __bf16 Xs[128][72];
    __shared__ __bf16 Ws[128][72];
    const int tid = threadIdx.x;
    const int wave = tid >> 6, lane = tid & 63;
    const int col = lane & 15, quad = lane >> 4;
    const int m_base = blockIdx.x * 128;
    const int j_base = blockIdx.y * 128;
    const bool qk = (j_base < 1024);
    const int wm = (wave & 1) * 64;
    const int wn = (wave >> 1) * 64;
    const f32x4 fz = {0.f, 0.f, 0.f, 0.f};
    f32x4 acc[4][4];
#pragma unroll
    for (int i = 0; i < 4; ++i)
#pragma unroll
        for (int j = 0; j < 4; ++j) acc[i][j] = fz;

    const int r = tid >> 3, c8 = (tid & 7) * 8;
    for (int k0 = 0; k0 < 512; k0 += 64) {
#pragma unroll
        for (int p = 0; p < 4; ++p) {
            *(bf16x8*)(&Xs[r + p * 32][c8]) =
                *(const bf16x8*)(X + (size_t)(m_base + r + p * 32) * 512 + k0 + c8);
            *(bf16x8*)(&Ws[r + p * 32][c8]) =
                *(const bf16x8*)(W + (size_t)(j_base + r + p * 32) * 512 + k0 + c8);
        }
        __syncthreads();
#pragma unroll
        for (int kk = 0; kk < 64; kk += 32) {
            bf16x8 xa[4], wb[4];
#pragma unroll
            for (int i = 0; i < 4; ++i) xa[i] = *(const bf16x8*)(&Xs[wm + i * 16 + col][kk + quad * 8]);
#pragma unroll
            for (int j = 0; j < 4; ++j) wb[j] = *(const bf16x8*)(&Ws[wn + j * 16 + col][kk + quad * 8]);
            if (qk) {
#pragma unroll
                for (int i = 0; i < 4; ++i)
#pragma unroll
                    for (int j = 0; j < 4; ++j)
                        acc[i][j] = __builtin_amdgcn_mfma_f32_16x16x32_bf16(wb[i], xa[j], acc[i][j], 0, 0, 0);
            } else {
#pragma unroll
                for (int i = 0; i < 4; ++i)
#pragma unroll
                    for (int j = 0; j < 4; ++j)
                        acc[i][j] = __builtin_amdgcn_mfma_f32_16x16x32_bf16(xa[i], wb[j], acc[i][j], 0, 0, 0);
            }
        }
        __syncthreads();
    }
    if (qk) {
#pragma unroll
        for (int i = 0; i < 4; ++i) {
#pragma unroll
            for (int j = 0; j < 4; ++j) {
                int jabs = j_base + wn + i * 16 + quad * 4;
                int m = m_base + wm + j * 16 + col;
                int b_ = m >> 10, n = m & 1023;
                int rem = jabs & 511, h = rem >> 6, d = rem & 63;
                __bf16* dst = (jabs >> 9) ? Kb : Qb;
                bf16x4 v;
                v[0] = (__bf16)acc[i][j][0]; v[1] = (__bf16)acc[i][j][1];
                v[2] = (__bf16)acc[i][j][2]; v[3] = (__bf16)acc[i][j][3];
                *(bf16x4*)(dst + (((size_t)b_ * 8 + h) * 1024 + n) * 64 + d) = v;
            }
        }
    } else {
#pragma unroll
        for (int i = 0; i < 4; ++i) {
#pragma unroll
            for (int j = 0; j < 4; ++j) {
                int m = m_base + wm + i * 16 + quad * 4;
                int b_ = m >> 10, nn = m & 1023;
                int jabs = j_base + wn + j * 16 + col;
                int rem = jabs & 511, h = rem >> 6, d = rem & 63;
                bf16x4 v;
                v[0] = (__bf16)acc[i][j][0]; v[1] = (__bf16)acc[i][j][1];
                v[2] = (__bf16)acc[i][j][2]; v[3] = (__bf16)acc[i][j][3];
                *(bf16x4*)(VbT + (((size_t)b_ * 8 + h) * 64 + d) * 1024 + nn) = v;
            }
        }
    }
}

// ---------------- flash attention, 32x32x16 MFMA, barrier-free ----------------
// grid: x = 16 (64-row n-tiles), y = 64 (b*h). 128 threads = 2 waves; each wave
// owns 32 Q-rows. K/V^T/E fragments read directly from global (L1/L2-hot).
// Only LDS use: wave-private P / O transpose staging.
__global__ __launch_bounds__(128) void flash_kernel(const __bf16* __restrict__ Qb,
                                                    const __bf16* __restrict__ Kb,
                                                    const __bf16* __restrict__ VbT,
                                                    const __bf16* __restrict__ Eb,
                                                    const float* __restrict__ phase,
                                                    __bf16* __restrict__ Ob) {
    const int bh = blockIdx.y;
    const int n0 = blockIdx.x * 64;
    const int w = threadIdx.x >> 6, lane = threadIdx.x & 63;
    const int colq = lane & 31, half = lane >> 5;
    const int nbase = n0 + w * 32;

    __shared__ __bf16 Pw[2][32][72];   // per-wave staging; pitch 72: conflict-free

    f32x16 z16;
#pragma unroll
    for (int i = 0; i < 16; ++i) z16[i] = 0.f;

    bf16x8 a_q[4];
#pragma unroll
    for (int ks = 0; ks < 4; ++ks)
        a_q[ks] = *(const bf16x8*)(Qb + ((size_t)bh * 1024 + nbase + colq) * 64 + ks * 16 + half * 8);

    f32x16 o0 = z16, o1 = z16;
    float rowsum[16];
#pragma unroll
    for (int i = 0; i < 16; ++i) rowsum[i] = 0.f;

    const __bf16* Kbase = Kb + (size_t)bh * 65536;
    const __bf16* Vbase = VbT + (size_t)bh * 65536;

#pragma unroll 1
    for (int m0 = 0; m0 < 1024; m0 += 64) {
        const int Wb = m0 - nbase + 992;           // E window base row (always >= 0)
        f32x16 qe0 = z16, qe1 = z16, qe2 = z16, s0 = z16, s1 = z16;
        const __bf16* ep = Eb + (size_t)(Wb + colq) * 64 + half * 8;
#pragma unroll
        for (int ks = 0; ks < 4; ++ks) {
            bf16x8 e0 = *(const bf16x8*)(ep + ks * 16);
            bf16x8 e1 = *(const bf16x8*)(ep + 32 * 64 + ks * 16);
            bf16x8 e2 = *(const bf16x8*)(ep + 64 * 64 + ks * 16);
            bf16x8 k0 = *(const bf16x8*)(Kbase + (size_t)(m0 + colq) * 64 + ks * 16 + half * 8);
            bf16x8 k1 = *(const bf16x8*)(Kbase + (size_t)(m0 + 32 + colq) * 64 + ks * 16 + half * 8);
            qe0 = __builtin_amdgcn_mfma_f32_32x32x16_bf16(a_q[ks], e0, qe0, 0, 0, 0);
            qe1 = __builtin_amdgcn_mfma_f32_32x32x16_bf16(a_q[ks], e1, qe1, 0, 0, 0);
            qe2 = __builtin_amdgcn_mfma_f32_32x32x16_bf16(a_q[ks], e2, qe2, 0, 0, 0);
            s0  = __builtin_amdgcn_mfma_f32_32x32x16_bf16(a_q[ks], k0, s0, 0, 0, 0);
            s1  = __builtin_amdgcn_mfma_f32_32x32x16_bf16(a_q[ks], k1, s1, 0, 0, 0);
        }
        // skew (shfl in 32-wide D-layout), exp2, P^T store
#pragma unroll
        for (int r = 0; r < 16; ++r) {
            int row = (r & 3) + 8 * (r >> 2) + 4 * half;
            int t = colq + 31 - row;               // 0..62
            int src = (t & 31) | (half << 5);
            float sh0 = __shfl(qe0[r], src, 64);
            float sh1 = __shfl(qe1[r], src, 64);
            float sh2 = __shfl(qe2[r], src, 64);
            bool sel = (t >= 32);
            float rel0 = sel ? sh1 : sh0;
            float rel1 = sel ? sh2 : sh1;
            float p0 = EXP2((s0[r] + rel0) * 0.18033688f);  // (1/8)*log2(e)
            float p1 = EXP2((s1[r] + rel1) * 0.18033688f);
            rowsum[r] += p0 + p1;
            Pw[w][row][colq]      = (__bf16)p0;
            Pw[w][row][32 + colq] = (__bf16)p1;
        }
        asm volatile("s_waitcnt lgkmcnt(0)" ::: "memory");
        // O += P @ V  (A-frag from Pw, B-frag = V^T rows direct from global)
#pragma unroll
        for (int ks = 0; ks < 4; ++ks) {
            bf16x8 pa = *(const bf16x8*)(&Pw[w][colq][ks * 16 + half * 8]);
            bf16x8 v0 = *(const bf16x8*)(Vbase + (size_t)colq * 1024 + m0 + ks * 16 + half * 8);
            bf16x8 v1 = *(const bf16x8*)(Vbase + (size_t)(32 + colq) * 1024 + m0 + ks * 16 + half * 8);
            o0 = __builtin_amdgcn_mfma_f32_32x32x16_bf16(pa, v0, o0, 0, 0, 0);
            o1 = __builtin_amdgcn_mfma_f32_32x32x16_bf16(pa, v1, o1, 0, 0, 0);
        }
        asm volatile("" ::: "memory");
    }

    // epilogue: l = row-sum reduce, scale by phase/l, store via Pw for coalescing
    const int b_ = bh >> 3, hh = bh & 7;
#pragma unroll
    for (int r = 0; r < 16; ++r) {
        float l = rowsum[r];
        l += __shfl_xor(l, 1, 32);
        l += __shfl_xor(l, 2, 32);
        l += __shfl_xor(l, 4, 32);
        l += __shfl_xor(l, 8, 32);
        l += __shfl_xor(l, 16, 32);
        int row = (r & 3) + 8 * (r >> 2) + 4 * half;
        float f = phase[(size_t)bh * 1024 + nbase + row] / l;
        Pw[w][row][colq]      = (__bf16)(o0[r] * f);
        Pw[w][row][32 + colq] = (__bf16)(o1[r] * f);
    }
    asm volatile("s_waitcnt lgkmcnt(0)" ::: "memory");
    {
        // R4 FIX: cover all 64 d-elements per row (R3 stored only 16 of 32 per slot).
        int row = lane >> 1, dseg = lane & 1;
        bf16x8 u0 = *(const bf16x8*)(&Pw[w][row][dseg * 32]);
        bf16x8 u1 = *(const bf16x8*)(&Pw[w][row][dseg * 32 + 8]);
        bf16x8 u2 = *(const bf16x8*)(&Pw[w][row][dseg * 32 + 16]);
        bf16x8 u3 = *(const bf16x8*)(&Pw[w][row][dseg * 32 + 24]);
        size_t obase = ((size_t)b_ * 1024 + nbase + row) * 512 + hh * 64 + dseg * 32;
        *(bf16x8*)(Ob + obase)      = u0;
        *(bf16x8*)(Ob + obase + 8)  = u1;
        *(bf16x8*)(Ob + obase + 16) = u2;
        *(bf16x8*)(Ob + obase + 24) = u3;
    }
}

// ---------------- output projection GEMM ----------------
// out[m][j] = sum_k Ob[m][k]*Wo[j][k] + b_o[j]; M=8192, N=512, K=512, fp32 out.
// Operand-swapped: acc regs run along j -> f32x4 16-B stores.
__global__ __launch_bounds__(256) void gemm_out(const __bf16* __restrict__ X,
                                                const __bf16* __restrict__ W,
                                                const float* __restrict__ bo,
                                                float* __restrict__ out) {
    __shared__ __bf16 Xs[128][72];
    __shared__ __bf16 Ws[128][72];
    const int tid = threadIdx.x;
    const int wave = tid >> 6, lane = tid & 63;
    const int col = lane & 15, quad = lane >> 4;
    const int m_base = blockIdx.x * 128;
    const int j_base = blockIdx.y * 128;
    const int wm = (wave & 1) * 64;
    const int wn = (wave >> 1) * 64;
    const f32x4 fz = {0.f, 0.f, 0.f, 0.f};
    f32x4 acc[4][4];
#pragma unroll
    for (int i = 0; i < 4; ++i)
#pragma unroll
        for (int j = 0; j < 4; ++j) acc[i][j] = fz;

    const int r = tid >> 3, c8 = (tid & 7) * 8;
    for (int k0 = 0; k0 < 512; k0 += 64) {
#pragma unroll
        for (int p = 0; p < 4; ++p) {
            *(bf16x8*)(&Xs[r + p * 32][c8]) =
                *(const bf16x8*)(X + (size_t)(m_base + r + p * 32) * 512 + k0 + c8);
            *(bf16x8*)(&Ws[r + p * 32][c8]) =
                *(const bf16x8*)(W + (size_t)(j_base + r + p * 32) * 512 + k0 + c8);
        }
        __syncthreads();
#pragma unroll
        for (int kk = 0; kk < 64; kk += 32) {
            bf16x8 xa[4], wb[4];
#pragma unroll
            for (int i = 0; i < 4; ++i) xa[i] = *(const bf16x8*)(&Xs[wm + i * 16 + col][kk + quad * 8]);
#pragma unroll
            for (int j = 0; j < 4; ++j) wb[j] = *(const bf16x8*)(&Ws[wn + j * 16 + col][kk + quad * 8]);
#pragma unroll
            for (int i = 0; i < 4; ++i)
#pragma unroll
                for (int j = 0; j < 4; ++j)
                    acc[i][j] = __builtin_amdgcn_mfma_f32_16x16x32_bf16(wb[i], xa[j], acc[i][j], 0, 0, 0);
        }
        __syncthreads();
    }
#pragma unroll
    for (int i = 0; i < 4; ++i) {
#pragma unroll
        for (int j = 0; j < 4; ++j) {
            int jabs = j_base + wn + i * 16 + quad * 4;
            int m = m_base + wm + j * 16 + col;
            f32x4 bv = *(const f32x4*)(bo + jabs);
            f32x4 o = acc[i][j] + bv;
            *(f32x4*)(out + (size_t)m * 512 + jabs) = o;
        }
    }
}

extern "C" void kernel_launch(void* const* d_in, const int* in_sizes, int n_in,
                              void* d_out, int out_size, void* d_ws, size_t ws_size,
                              hipStream_t stream) {
    (void)in_sizes; (void)n_in; (void)out_size; (void)ws_size;
    const float* x     = (const float*)d_in[0];
    const float* phase = (const float*)d_in[1];
    const float* E_rel = (const float*)d_in[2];
    const float* W_q   = (const float*)d_in[3];
    const float* W_k   = (const float*)d_in[4];
    const float* W_v   = (const float*)d_in[5];
    const float* W_o   = (const float*)d_in[6];
    const float* b_o   = (const float*)d_in[7];
    float* out = (float*)d_out;

    char* ws = (char*)d_ws;
    __bf16* xb   = (__bf16*)(ws);                 //  8,388,608 B
    __bf16* wqkv = (__bf16*)(ws + 8388608);       //  1,572,864 B (q|k|v rows stacked)
    __bf16* wob  = (__bf16*)(ws + 9961472);       //    524,288 B
    __bf16* Eb   = (__bf16*)(ws + 10485760);      //    262,144 B (2048 rows; row 2047 never selected)
    __bf16* Qb   = (__bf16*)(ws + 10747904);      //  8,388,608 B
    __bf16* Kb   = (__bf16*)(ws + 19136512);      //  8,388,608 B
    __bf16* VbT  = (__bf16*)(ws + 27525120);      //  8,388,608 B  [B,H,dh,N]
    __bf16* Ob   = (__bf16*)(ws + 35913728);      //  8,388,608 B

    cvt_all<<<dim3(5249), dim3(256), 0, stream>>>(x, E_rel, W_q, W_k, W_v, W_o,
                                                  xb, Eb, wqkv, wob);
    gemm_qkv<<<dim3(64, 12), dim3(256), 0, stream>>>(xb, wqkv, Qb, Kb, VbT);
    flash_kernel<<<dim3(16, 64), dim3(128), 0, stream>>>(Qb, Kb, VbT, Eb, phase, Ob);
    gemm_out<<<dim3(64, 4), dim3(256), 0, stream>>>(Ob, wob, b_o, out);
}

// Round 5
// 199.153 us; speedup vs baseline: 1.2985x; 1.1440x over previous
//
#include <hip/hip_runtime.h>

// PhaseMultiHeadAttention: B=8, N=1024, D=512, H=8, dh=64
// R5: K/V/E precomputed in MFMA-fragment-stream layout (lane-contiguous 1KB
// wave loads kill the TA address-divergence that bound R4's flash at 116us);
// GEMMs use global_load_lds width-16 staging (m97 pattern).
// rel[n,m] = Q[n] . E_rel[m-n+N-1]

typedef __bf16 bf16x8 __attribute__((ext_vector_type(8)));
typedef __bf16 bf16x4 __attribute__((ext_vector_type(4)));
typedef float  f32x4  __attribute__((ext_vector_type(4)));
typedef float  f32x16 __attribute__((ext_vector_type(16)));

#if __has_builtin(__builtin_amdgcn_exp2f)
#define EXP2(x) __builtin_amdgcn_exp2f(x)
#else
#define EXP2(x) exp2f(x)
#endif

// async global->LDS, 16B per lane; LDS dest = wave-uniform base + lane*16
#define GLOAD_LDS16(g, l)                                                      \
    __builtin_amdgcn_global_load_lds(                                          \
        (const __attribute__((address_space(1))) unsigned int*)(g),            \
        (__attribute__((address_space(3))) unsigned int*)(l), 16, 0, 0)

// Fragment-stream layouts (per bh, 65536 elems = 128KB):
//  Kf: [t32 = n>>5][ks = d>>4][lane = ((d>>3)&1)*32 + (n&31)][j = d&7]
//  Vf: [t64 = n>>6][ks = (n>>4)&3][dhalf = d>>5][lane = ((n>>3)&1)*32 + (d&31)][j = n&7]
//  Ef: like Kf over 2048 rows (l = row index): [t32 = l>>5][ks][lane][j]

// ---------------- fused fp32 -> bf16 conversion ----------------
__global__ __launch_bounds__(256) void cvt_all(const float* __restrict__ x,
                                               const float* __restrict__ E,
                                               const float* __restrict__ wq,
                                               const float* __restrict__ wk,
                                               const float* __restrict__ wv,
                                               const float* __restrict__ wo,
                                               __bf16* __restrict__ xb,
                                               __bf16* __restrict__ Ef,
                                               __bf16* __restrict__ wqkv,
                                               __bf16* __restrict__ wob) {
    int i = blockIdx.x * 256 + threadIdx.x;
    if (i >= 1081328 ? i < 1343472 : i < 1048576) {
        // plain contiguous tensors
        const float* s; __bf16* d; int off;
        if      (i < 1048576) { s = x;  d = xb;            off = i; }
        else if (i < 1146864) { s = wq; d = wqkv;          off = i - 1081328; }
        else if (i < 1212400) { s = wk; d = wqkv + 262144; off = i - 1146864; }
        else if (i < 1277936) { s = wv; d = wqkv + 524288; off = i - 1212400; }
        else                  { s = wo; d = wob;           off = i - 1277936; }
        float4 v = *(const float4*)(s + (size_t)off * 4);
        bf16x4 o;
        o[0] = (__bf16)v.x; o[1] = (__bf16)v.y; o[2] = (__bf16)v.z; o[3] = (__bf16)v.w;
        *(bf16x4*)(d + (size_t)off * 4) = o;
    } else if (i >= 1048576 && i < 1081328) {
        // E -> fragment stream
        int off = i - 1048576;          // float4 group over 2047*64 elems
        float4 v = *(const float4*)(E + (size_t)off * 4);
        int e0i = off * 4;
        int l = e0i >> 6, d0 = e0i & 63;
        int t32 = l >> 5, cq = l & 31, ks = d0 >> 4, hf = (d0 >> 3) & 1, j = d0 & 7;
        bf16x4 o;
        o[0] = (__bf16)v.x; o[1] = (__bf16)v.y; o[2] = (__bf16)v.z; o[3] = (__bf16)v.w;
        *(bf16x4*)(Ef + ((size_t)((t32 * 4 + ks) * 64) + hf * 32 + cq) * 8 + j) = o;
    }
}

// ---------------- QKV projection GEMM ----------------
// C[m][j] = sum_k X[m][k]*W[j][k]; M=8192, N=1536 (q|k|v), K=512.
// global_load_lds staging; epilogue: Q normal layout, K/V fragment streams.
__global__ __launch_bounds__(256) void gemm_qkv(const __bf16* __restrict__ X,
                                                const __bf16* __restrict__ W,
                                                __bf16* __restrict__ Qb,
                                                __bf16* __restrict__ Kf,
                                                __bf16* __restrict__ Vf) {
    __shared__ __bf16 Xs[128][64];
    __shared__ __bf16 Ws[128][64];
    const int tid = threadIdx.x;
    const int wave = tid >> 6, lane = tid & 63;
    const int col = lane & 15, quad = lane >> 4;
    const int m_base = blockIdx.x * 128;
    const int j_base = blockIdx.y * 128;
    const bool qk = (j_base < 1024);
    const int wm = (wave & 1) * 64;
    const int wn = (wave >> 1) * 64;
    const f32x4 fz = {0.f, 0.f, 0.f, 0.f};
    f32x4 acc[4][4];
#pragma unroll
    for (int i = 0; i < 4; ++i)
#pragma unroll
        for (int j = 0; j < 4; ++j) acc[i][j] = fz;

    for (int k0 = 0; k0 < 512; k0 += 64) {
#pragma unroll
        for (int p = 0; p < 4; ++p) {
            int s = tid + p * 256;              // 0..1023 16B slots
            int row = s >> 3, cc = (s & 7) * 8;
            GLOAD_LDS16(X + (size_t)(m_base + row) * 512 + k0 + cc, &Xs[0][0] + (size_t)s * 8);
            GLOAD_LDS16(W + (size_t)(j_base + row) * 512 + k0 + cc, &Ws[0][0] + (size_t)s * 8);
        }
        __syncthreads();
#pragma unroll
        for (int kk = 0; kk < 64; kk += 32) {
            bf16x8 xa[4], wb[4];
#pragma unroll
            for (int i = 0; i < 4; ++i) xa[i] = *(const bf16x8*)(&Xs[wm + i * 16 + col][kk + quad * 8]);
#pragma unroll
            for (int j = 0; j < 4; ++j) wb[j] = *(const bf16x8*)(&Ws[wn + j * 16 + col][kk + quad * 8]);
            if (qk) {
#pragma unroll
                for (int i = 0; i < 4; ++i)
#pragma unroll
                    for (int j = 0; j < 4; ++j)
                        acc[i][j] = __builtin_amdgcn_mfma_f32_16x16x32_bf16(wb[i], xa[j], acc[i][j], 0, 0, 0);
            } else {
#pragma unroll
                for (int i = 0; i < 4; ++i)
#pragma unroll
                    for (int j = 0; j < 4; ++j)
                        acc[i][j] = __builtin_amdgcn_mfma_f32_16x16x32_bf16(xa[i], wb[j], acc[i][j], 0, 0, 0);
            }
        }
        __syncthreads();
    }
    if (qk) {
        // acc regs pack 4 consecutive jabs (= d); rows jabs, cols m
#pragma unroll
        for (int i = 0; i < 4; ++i) {
#pragma unroll
            for (int j = 0; j < 4; ++j) {
                int jabs = j_base + wn + i * 16 + quad * 4;
                int m = m_base + wm + j * 16 + col;
                int b_ = m >> 10, n = m & 1023;
                int rem = jabs & 511, h = rem >> 6, d = rem & 63;
                bf16x4 v;
                v[0] = (__bf16)acc[i][j][0]; v[1] = (__bf16)acc[i][j][1];
                v[2] = (__bf16)acc[i][j][2]; v[3] = (__bf16)acc[i][j][3];
                if (jabs < 512) {
                    *(bf16x4*)(Qb + (((size_t)b_ * 8 + h) * 1024 + n) * 64 + d) = v;
                } else {
                    int t32 = n >> 5, cq = n & 31, ks = d >> 4, hf = (d >> 3) & 1, jj = d & 7;
                    *(bf16x4*)(Kf + (size_t)(b_ * 8 + h) * 65536 +
                               ((size_t)((t32 * 4 + ks) * 64) + hf * 32 + cq) * 8 + jj) = v;
                }
            }
        }
    } else {
        // acc regs pack 4 consecutive m (= n); rows m, cols jabs
#pragma unroll
        for (int i = 0; i < 4; ++i) {
#pragma unroll
            for (int j = 0; j < 4; ++j) {
                int m = m_base + wm + i * 16 + quad * 4;
                int b_ = m >> 10, n = m & 1023;
                int jabs = j_base + wn + j * 16 + col;
                int rem = jabs & 511, h = rem >> 6, d = rem & 63;
                int t64 = n >> 6, ks = (n >> 4) & 3, hf = (n >> 3) & 1, jj = n & 7;
                int dhalf = d >> 5, cq = d & 31;
                bf16x4 v;
                v[0] = (__bf16)acc[i][j][0]; v[1] = (__bf16)acc[i][j][1];
                v[2] = (__bf16)acc[i][j][2]; v[3] = (__bf16)acc[i][j][3];
                *(bf16x4*)(Vf + (size_t)(b_ * 8 + h) * 65536 +
                           ((size_t)(((t64 * 4 + ks) * 2 + dhalf) * 64) + hf * 32 + cq) * 8 + jj) = v;
            }
        }
    }
}

// ---------------- flash attention, fragment-stream loads, barrier-free ----------------
// grid: x = 16 (64-row n-tiles), y = 64 (b*h). 128 threads = 2 waves, 32 rows each.
__global__ __launch_bounds__(128) void flash_kernel(const __bf16* __restrict__ Qb,
                                                    const __bf16* __restrict__ Kf,
                                                    const __bf16* __restrict__ Vf,
                                                    const __bf16* __restrict__ Ef,
                                                    const float* __restrict__ phase,
                                                    __bf16* __restrict__ Ob) {
    const int bh = blockIdx.y;
    const int n0 = blockIdx.x * 64;
    const int w = threadIdx.x >> 6, lane = threadIdx.x & 63;
    const int colq = lane & 31, half = lane >> 5;
    const int nbase = n0 + w * 32;

    __shared__ __bf16 Pw[2][32][72];   // per-wave staging; conflict-free

    f32x16 z16;
#pragma unroll
    for (int i = 0; i < 16; ++i) z16[i] = 0.f;

    bf16x8 a_q[4];
#pragma unroll
    for (int ks = 0; ks < 4; ++ks)
        a_q[ks] = *(const bf16x8*)(Qb + ((size_t)bh * 1024 + nbase + colq) * 64 + ks * 16 + half * 8);

    f32x16 o0 = z16, o1 = z16;
    float rowsum[16];
#pragma unroll
    for (int i = 0; i < 16; ++i) rowsum[i] = 0.f;

    const __bf16* Kfb = Kf + (size_t)bh * 65536;
    const __bf16* Vfb = Vf + (size_t)bh * 65536;

#pragma unroll 1
    for (int m0 = 0; m0 < 1024; m0 += 64) {
        const int t32 = m0 >> 5;
        const int te = (m0 - nbase + 992) >> 5;   // E window 32-tile (always >= 0)
        f32x16 qe0 = z16, qe1 = z16, qe2 = z16, s0 = z16, s1 = z16;
#pragma unroll
        for (int ks = 0; ks < 4; ++ks) {
            bf16x8 e0 = *(const bf16x8*)(Ef + ((size_t)((te * 4 + ks) * 64) + lane) * 8);
            bf16x8 e1 = *(const bf16x8*)(Ef + ((size_t)(((te + 1) * 4 + ks) * 64) + lane) * 8);
            bf16x8 e2 = *(const bf16x8*)(Ef + ((size_t)(((te + 2) * 4 + ks) * 64) + lane) * 8);
            bf16x8 k0 = *(const bf16x8*)(Kfb + ((size_t)((t32 * 4 + ks) * 64) + lane) * 8);
            bf16x8 k1 = *(const bf16x8*)(Kfb + ((size_t)(((t32 + 1) * 4 + ks) * 64) + lane) * 8);
            qe0 = __builtin_amdgcn_mfma_f32_32x32x16_bf16(a_q[ks], e0, qe0, 0, 0, 0);
            qe1 = __builtin_amdgcn_mfma_f32_32x32x16_bf16(a_q[ks], e1, qe1, 0, 0, 0);
            qe2 = __builtin_amdgcn_mfma_f32_32x32x16_bf16(a_q[ks], e2, qe2, 0, 0, 0);
            s0  = __builtin_amdgcn_mfma_f32_32x32x16_bf16(a_q[ks], k0, s0, 0, 0, 0);
            s1  = __builtin_amdgcn_mfma_f32_32x32x16_bf16(a_q[ks], k1, s1, 0, 0, 0);
        }
        // skew (shfl in 32-wide D-layout), exp2, P^T store
#pragma unroll
        for (int r = 0; r < 16; ++r) {
            int row = (r & 3) + 8 * (r >> 2) + 4 * half;
            int t = colq + 31 - row;               // 0..62
            int src = (t & 31) | (half << 5);
            float sh0 = __shfl(qe0[r], src, 64);
            float sh1 = __shfl(qe1[r], src, 64);
            float sh2 = __shfl(qe2[r], src, 64);
            bool sel = (t >= 32);
            float rel0 = sel ? sh1 : sh0;
            float rel1 = sel ? sh2 : sh1;
            float p0 = EXP2((s0[r] + rel0) * 0.18033688f);  // (1/8)*log2(e)
            float p1 = EXP2((s1[r] + rel1) * 0.18033688f);
            rowsum[r] += p0 + p1;
            Pw[w][row][colq]      = (__bf16)p0;
            Pw[w][row][32 + colq] = (__bf16)p1;
        }
        asm volatile("s_waitcnt lgkmcnt(0)" ::: "memory");
        // O += P @ V  (A-frag from Pw, B-frag = Vf fragment stream)
#pragma unroll
        for (int ks = 0; ks < 4; ++ks) {
            bf16x8 pa = *(const bf16x8*)(&Pw[w][colq][ks * 16 + half * 8]);
            bf16x8 v0 = *(const bf16x8*)(Vfb + ((size_t)((((m0 >> 6) * 4 + ks) * 2 + 0) * 64) + lane) * 8);
            bf16x8 v1 = *(const bf16x8*)(Vfb + ((size_t)((((m0 >> 6) * 4 + ks) * 2 + 1) * 64) + lane) * 8);
            o0 = __builtin_amdgcn_mfma_f32_32x32x16_bf16(pa, v0, o0, 0, 0, 0);
            o1 = __builtin_amdgcn_mfma_f32_32x32x16_bf16(pa, v1, o1, 0, 0, 0);
        }
        asm volatile("" ::: "memory");
    }

    // epilogue: l reduce, scale by phase/l, store via Pw for coalescing
    const int b_ = bh >> 3, hh = bh & 7;
#pragma unroll
    for (int r = 0; r < 16; ++r) {
        float l = rowsum[r];
        l += __shfl_xor(l, 1, 32);
        l += __shfl_xor(l, 2, 32);
        l += __shfl_xor(l, 4, 32);
        l += __shfl_xor(l, 8, 32);
        l += __shfl_xor(l, 16, 32);
        int row = (r & 3) + 8 * (r >> 2) + 4 * half;
        float f = phase[(size_t)bh * 1024 + nbase + row] / l;
        Pw[w][row][colq]      = (__bf16)(o0[r] * f);
        Pw[w][row][32 + colq] = (__bf16)(o1[r] * f);
    }
    asm volatile("s_waitcnt lgkmcnt(0)" ::: "memory");
    {
        int row = lane >> 1, dseg = lane & 1;
        bf16x8 u0 = *(const bf16x8*)(&Pw[w][row][dseg * 32]);
        bf16x8 u1 = *(const bf16x8*)(&Pw[w][row][dseg * 32 + 8]);
        bf16x8 u2 = *(const bf16x8*)(&Pw[w][row][dseg * 32 + 16]);
        bf16x8 u3 = *(const bf16x8*)(&Pw[w][row][dseg * 32 + 24]);
        size_t obase = ((size_t)b_ * 1024 + nbase + row) * 512 + hh * 64 + dseg * 32;
        *(bf16x8*)(Ob + obase)      = u0;
        *(bf16x8*)(Ob + obase + 8)  = u1;
        *(bf16x8*)(Ob + obase + 16) = u2;
        *(bf16x8*)(Ob + obase + 24) = u3;
    }
}

// ---------------- output projection GEMM ----------------
// out[m][j] = sum_k Ob[m][k]*Wo[j][k] + b_o[j]; M=8192, N=512, K=512, fp32 out.
__global__ __launch_bounds__(256) void gemm_out(const __bf16* __restrict__ X,
                                                const __bf16* __restrict__ W,
                                                const float* __restrict__ bo,
                                                float* __restrict__ out) {
    __shared__ __bf16 Xs[128][64];
    __shared__ __bf16 Ws[128][64];
    const int tid = threadIdx.x;
    const int wave = tid >> 6, lane = tid & 63;
    const int col = lane & 15, quad = lane >> 4;
    const int m_base = blockIdx.x * 128;
    const int j_base = blockIdx.y * 128;
    const int wm = (wave & 1) * 64;
    const int wn = (wave >> 1) * 64;
    const f32x4 fz = {0.f, 0.f, 0.f, 0.f};
    f32x4 acc[4][4];
#pragma unroll
    for (int i = 0; i < 4; ++i)
#pragma unroll
        for (int j = 0; j < 4; ++j) acc[i][j] = fz;

    for (int k0 = 0; k0 < 512; k0 += 64) {
#pragma unroll
        for (int p = 0; p < 4; ++p) {
            int s = tid + p * 256;
            int row = s >> 3, cc = (s & 7) * 8;
            GLOAD_LDS16(X + (size_t)(m_base + row) * 512 + k0 + cc, &Xs[0][0] + (size_t)s * 8);
            GLOAD_LDS16(W + (size_t)(j_base + row) * 512 + k0 + cc, &Ws[0][0] + (size_t)s * 8);
        }
        __syncthreads();
#pragma unroll
        for (int kk = 0; kk < 64; kk += 32) {
            bf16x8 xa[4], wb[4];
#pragma unroll
            for (int i = 0; i < 4; ++i) xa[i] = *(const bf16x8*)(&Xs[wm + i * 16 + col][kk + quad * 8]);
#pragma unroll
            for (int j = 0; j < 4; ++j) wb[j] = *(const bf16x8*)(&Ws[wn + j * 16 + col][kk + quad * 8]);
#pragma unroll
            for (int i = 0; i < 4; ++i)
#pragma unroll
                for (int j = 0; j < 4; ++j)
                    acc[i][j] = __builtin_amdgcn_mfma_f32_16x16x32_bf16(wb[i], xa[j], acc[i][j], 0, 0, 0);
        }
        __syncthreads();
    }
#pragma unroll
    for (int i = 0; i < 4; ++i) {
#pragma unroll
        for (int j = 0; j < 4; ++j) {
            int jabs = j_base + wn + i * 16 + quad * 4;
            int m = m_base + wm + j * 16 + col;
            f32x4 bv = *(const f32x4*)(bo + jabs);
            f32x4 o = acc[i][j] + bv;
            *(f32x4*)(out + (size_t)m * 512 + jabs) = o;
        }
    }
}

extern "C" void kernel_launch(void* const* d_in, const int* in_sizes, int n_in,
                              void* d_out, int out_size, void* d_ws, size_t ws_size,
                              hipStream_t stream) {
    (void)in_sizes; (void)n_in; (void)out_size; (void)ws_size;
    const float* x     = (const float*)d_in[0];
    const float* phase = (const float*)d_in[1];
    const float* E_rel = (const float*)d_in[2];
    const float* W_q   = (const float*)d_in[3];
    const float* W_k   = (const float*)d_in[4];
    const float* W_v   = (const float*)d_in[5];
    const float* W_o   = (const float*)d_in[6];
    const float* b_o   = (const float*)d_in[7];
    float* out = (float*)d_out;

    char* ws = (char*)d_ws;
    __bf16* xb   = (__bf16*)(ws);                 //  8,388,608 B
    __bf16* wqkv = (__bf16*)(ws + 8388608);       //  1,572,864 B (q|k|v rows stacked)
    __bf16* wob  = (__bf16*)(ws + 9961472);       //    524,288 B
    __bf16* Ef   = (__bf16*)(ws + 10485760);      //    262,144 B fragment stream (row 2047 poison, never selected)
    __bf16* Qb   = (__bf16*)(ws + 10747904);      //  8,388,608 B
    __bf16* Kf   = (__bf16*)(ws + 19136512);      //  8,388,608 B fragment stream
    __bf16* Vf   = (__bf16*)(ws + 27525120);      //  8,388,608 B fragment stream
    __bf16* Ob   = (__bf16*)(ws + 35913728);      //  8,388,608 B

    cvt_all<<<dim3(5249), dim3(256), 0, stream>>>(x, E_rel, W_q, W_k, W_v, W_o,
                                                  xb, Ef, wqkv, wob);
    gemm_qkv<<<dim3(64, 12), dim3(256), 0, stream>>>(xb, wqkv, Qb, Kf, Vf);
    flash_kernel<<<dim3(16, 64), dim3(128), 0, stream>>>(Qb, Kf, Vf, Ef, phase, Ob);
    gemm_out<<<dim3(64, 4), dim3(256), 0, stream>>>(Ob, wob, b_o, out);
}